// Round 8
// baseline (77.773 us; speedup 1.0000x reference)
//
#include <hip/hip_runtime.h>
#include <hip/hip_bf16.h>

// Mamba block: B=4, L=512, D_MODEL=128, D_INNER=D_STATE=256
// [proj(MFMA, fp32 in-kernel convert/transpose) + weight-prep blocks]
// -> dbc(MFMA) -> chunked 3-pass scan (NC=16, LC=32, D_REP=4, Taylor exp)
// -> out GEMM (MFMA, fuses *silu(z))

#define MROWS 2048   // B*L
#define DM 128
#define DI 256
#define DS 256
#define LLEN 512
#define LC 32        // chunk length
#define NC 16        // chunks

#define LOG2E 1.44269504088896340736f

typedef short bf16x8 __attribute__((ext_vector_type(8)));
typedef float f32x4  __attribute__((ext_vector_type(4)));

__device__ __forceinline__ short f2bf(float f) {
    union { float f; unsigned u; } v; v.f = f;
    unsigned r = v.u + 0x7FFFu + ((v.u >> 16) & 1u);   // RNE
    return (short)(r >> 16);
}

// Taylor-3 exp(a*dl), Horner: per-lane consts c1=a, c2=a^2/2, c3=a^3/6.
#define TEXP(c1, c2, c3, dl) fmaf(fmaf(fmaf((c3), (dl), (c2)), (dl), (c1)), (dl), 1.f)

// ---------------------------------------------------------------------------
// 32x32 transpose+convert tile (fp32 src -> bf16 dst, dst N-major)
// ---------------------------------------------------------------------------
__device__ __forceinline__ void tconv(float (*tile)[33],
                                      const float* __restrict__ src,
                                      short* __restrict__ dst,
                                      int Ms, int Ns, int ti, int tj, int tid)
{
    const int r = tid >> 5, c = tid & 31;
#pragma unroll
    for (int i = 0; i < 4; ++i)
        tile[r + 8 * i][c] = src[(size_t)(ti * 32 + r + 8 * i) * Ns + tj * 32 + c];
    __syncthreads();
#pragma unroll
    for (int i = 0; i < 4; ++i)
        dst[(size_t)(tj * 32 + r + 8 * i) * Ms + ti * 32 + c] = f2bf(tile[c][r + 8 * i]);
}

// ---------------------------------------------------------------------------
// kernel 1: in_proj (MFMA) + fused weight-prep blocks
// grid (15, 32): bx<8 -> GEMM tile (r0=by*64, n0=bx*64); bx>=8 -> prep
// GEMM: A = x fp32 (convert on stage), B = W_in fp32 (transposed stage),
// full K=128 in LDS, one barrier, 16 MFMA.
// ---------------------------------------------------------------------------
__global__ __launch_bounds__(256) void k_proj_mfma(
    const float* __restrict__ x, const float* __restrict__ W_in,
    const float* __restrict__ Wd, const float* __restrict__ Wb,
    const float* __restrict__ Wc, const float* __restrict__ W_out,
    float* __restrict__ xs, short* __restrict__ xs_bf, float* __restrict__ sz,
    short* __restrict__ WdbcT, short* __restrict__ W_outT)
{
    const int t = threadIdx.x;

    if (blockIdx.x >= 8) {               // ---- prep role: 224 tiles ----
        __shared__ float tile[32][33];
        const int uu = (blockIdx.x - 8) * 32 + blockIdx.y;
        if (uu < 64)       tconv(tile, Wd,    WdbcT,                       256, 256, uu & 7,         uu >> 3,         t);
        else if (uu < 128) tconv(tile, Wb,    WdbcT + (size_t)256 * 256,   256, 256, (uu - 64) & 7,  (uu - 64) >> 3,  t);
        else if (uu < 192) tconv(tile, Wc,    WdbcT + (size_t)512 * 256,   256, 256, (uu - 128) & 7, (uu - 128) >> 3, t);
        else if (uu < 224) tconv(tile, W_out, W_outT,                      256, 128, (uu - 192) & 7, (uu - 192) >> 3, t);
        return;
    }

    // ---- GEMM role ----
    __shared__ short As[64][136];        // 64 rows x K=128 (+8 pad)
    __shared__ short Bs[64][136];        // 64 n-rows x K=128 (+8 pad)
    f32x4 acc[4] = {};
    const int w = t >> 6, lane = t & 63;
    const int srow = t >> 2, sseg = t & 3;
    const int frow = lane & 15, fk = (lane >> 4) << 3;
    const int r0 = blockIdx.y * 64, n0 = blockIdx.x * 64;

    // stage A: x rows r0+srow, k = sseg*32..+32, convert fp32->bf16
    {
        const float* ap = x + (size_t)(r0 + srow) * DM + sseg * 32;
        short tmp[32];
#pragma unroll
        for (int j = 0; j < 8; ++j) {
            float4 f = *(const float4*)(ap + j * 4);
            tmp[j * 4 + 0] = f2bf(f.x); tmp[j * 4 + 1] = f2bf(f.y);
            tmp[j * 4 + 2] = f2bf(f.z); tmp[j * 4 + 3] = f2bf(f.w);
        }
#pragma unroll
        for (int m = 0; m < 4; ++m)
            *(bf16x8*)&As[srow][sseg * 32 + m * 8] = *(bf16x8*)&tmp[m * 8];
    }
    // stage B transposed: Bs[n][k] = W_in[k][n0+n]; coalesced along n
    {
#pragma unroll
        for (int i = 0; i < 32; i += 2) {
            const int k = sseg * 32 + i;
            float f0 = W_in[(size_t)k * 512 + n0 + srow];
            float f1 = W_in[(size_t)(k + 1) * 512 + n0 + srow];
            unsigned pk = (unsigned short)f2bf(f0) | ((unsigned)(unsigned short)f2bf(f1) << 16);
            *(unsigned*)&Bs[srow][k] = pk;
        }
    }
    __syncthreads();

#pragma unroll
    for (int kk = 0; kk < 128; kk += 32) {
        bf16x8 af = *(const bf16x8*)&As[w * 16 + frow][kk + fk];
#pragma unroll
        for (int ct = 0; ct < 4; ++ct) {
            bf16x8 bfr = *(const bf16x8*)&Bs[ct * 16 + frow][kk + fk];
            acc[ct] = __builtin_amdgcn_mfma_f32_16x16x32_bf16(af, bfr, acc[ct], 0, 0, 0);
        }
    }

    const int rr = r0 + w * 16 + (lane >> 4) * 4;
    const int c0 = n0 + (lane & 15);
#pragma unroll
    for (int ct = 0; ct < 4; ++ct) {
        const int c = c0 + ct * 16;
#pragma unroll
        for (int rg = 0; rg < 4; ++rg) {
            const float v = acc[ct][rg];
            const int r = rr + rg;
            if (c < DI) {
                xs[(size_t)r * DI + c]    = v;
                xs_bf[(size_t)r * DI + c] = f2bf(v);
            } else {
                sz[(size_t)r * DI + (c - DI)] = v / (1.f + __expf(-v));
            }
        }
    }
}

// ---------------------------------------------------------------------------
// MFMA GEMM core (64x64 tile, BK=64 staging loop) — used by k_dbc
// ---------------------------------------------------------------------------
#define BKK 64
#define LP  72

__device__ __forceinline__ void mfma_core64(
    const short* __restrict__ Abf, int lda,
    const short* __restrict__ BbfT, int ldb,
    int K, int r0, int n0,
    short (*As)[LP], short (*Bs)[LP], f32x4 acc[4])
{
    const int tid  = threadIdx.x;
    const int w    = tid >> 6, lane = tid & 63;
    const int srow = tid >> 2, sseg = tid & 3;
    const int frow = lane & 15, fk = (lane >> 4) << 3;

    for (int k0 = 0; k0 < K; k0 += BKK) {
        const short* ag = Abf  + (size_t)(r0 + srow) * lda + k0 + sseg * 16;
        const short* bg = BbfT + (size_t)(n0 + srow) * ldb + k0 + sseg * 16;
        bf16x8 a0 = *(const bf16x8*)ag;
        bf16x8 a1 = *(const bf16x8*)(ag + 8);
        bf16x8 b0 = *(const bf16x8*)bg;
        bf16x8 b1 = *(const bf16x8*)(bg + 8);
        __syncthreads();
        *(bf16x8*)&As[srow][sseg * 16]     = a0;
        *(bf16x8*)&As[srow][sseg * 16 + 8] = a1;
        *(bf16x8*)&Bs[srow][sseg * 16]     = b0;
        *(bf16x8*)&Bs[srow][sseg * 16 + 8] = b1;
        __syncthreads();
#pragma unroll
        for (int kk = 0; kk < BKK; kk += 32) {
            bf16x8 af = *(const bf16x8*)&As[w * 16 + frow][kk + fk];
#pragma unroll
            for (int ct = 0; ct < 4; ++ct) {
                bf16x8 bfr = *(const bf16x8*)&Bs[ct * 16 + frow][kk + fk];
                acc[ct] = __builtin_amdgcn_mfma_f32_16x16x32_bf16(af, bfr, acc[ct], 0, 0, 0);
            }
        }
    }
}

// ------------------- kernel 2: delta / u=Bv*xs / Cv (MFMA) ------------------
__global__ __launch_bounds__(256) void k_dbc_mfma(
    const short* __restrict__ xs_bf, const short* __restrict__ WdbcT,
    const float* __restrict__ xs,
    float* __restrict__ dlt, float* __restrict__ u, float* __restrict__ cvv)
{
    __shared__ short As[64][LP], Bs[64][LP];
    f32x4 acc[4] = {};
    const int r0 = blockIdx.y * 64, n0 = blockIdx.x * 64;
    mfma_core64(xs_bf, DI, WdbcT, DI, DI, r0, n0, As, Bs, acc);
    const int lane = threadIdx.x & 63, w = threadIdx.x >> 6;
    const int rr = r0 + w * 16 + (lane >> 4) * 4;
    const int wsel = n0 >> 8;          // 0: delta, 1: B, 2: C
    const int nb = n0 & 255;
#pragma unroll
    for (int ct = 0; ct < 4; ++ct) {
        const int c = nb + ct * 16 + (lane & 15);
#pragma unroll
        for (int rg = 0; rg < 4; ++rg) {
            const float v = acc[ct][rg];
            const size_t idx = (size_t)(rr + rg) * DI + c;
            if (wsel == 0)      dlt[idx] = v;
            else if (wsel == 1) u[idx]   = v * xs[idx];   // Bv * xs
            else                cvv[idx] = v;
        }
    }
}

// ------------------------ chunked scan: NC=16, LC=32 ------------------------
// 1024 blocks x 4 waves; wave owns 4 consecutive d (d0..d0+3) of one (b,c).

// --------------------- scan pass 1: chunk-local states ----------------------
__global__ __launch_bounds__(256, 4) void k_scan1(
    const float* __restrict__ dlt, const float* __restrict__ u,
    const float* __restrict__ A,
    float* __restrict__ tc, float* __restrict__ dsum)
{
    const int lane = threadIdx.x & 63;
    const int w    = threadIdx.x >> 6;
    const int blk  = blockIdx.x;
    const int b  = blk & 3;
    const int c  = (blk >> 2) & 15;
    const int d0 = ((blk >> 6) * 4 + w) * 4;

    __shared__ float dls[4][4][LC];

    const size_t base = (size_t)b * LLEN * DI + (size_t)c * LC * DI;

    float4 dv = make_float4(0.f, 0.f, 0.f, 0.f);
    if (lane < LC) {
        dv = *(const float4*)(dlt + base + (size_t)lane * DI + d0);
        dls[w][0][lane] = dv.x;
        dls[w][1][lane] = dv.y;
        dls[w][2][lane] = dv.z;
        dls[w][3][lane] = dv.w;
    }
    float dsv[4] = { dv.x, dv.y, dv.z, dv.w };
#pragma unroll
    for (int dd = 0; dd < 4; ++dd) {
#pragma unroll
        for (int off = 32; off > 0; off >>= 1)
            dsv[dd] += __shfl_xor(dsv[dd], off);
    }

    float4 c1[4], c2[4], c3[4];
#pragma unroll
    for (int dd = 0; dd < 4; ++dd) {
        float4 a = *(const float4*)(A + (size_t)(d0 + dd) * DS + lane * 4);
        c1[dd] = a;
        c2[dd] = make_float4(0.5f * a.x * a.x, 0.5f * a.y * a.y,
                             0.5f * a.z * a.z, 0.5f * a.w * a.w);
        c3[dd] = make_float4(c2[dd].x * a.x * (1.f / 3.f), c2[dd].y * a.y * (1.f / 3.f),
                             c2[dd].z * a.z * (1.f / 3.f), c2[dd].w * a.w * (1.f / 3.f));
    }

    const float4* up = (const float4*)(u + base) + lane;
    float4 s[4] = {};

    for (int g = 0; g < LC / 4; ++g) {           // 8 groups of 4 steps
        float4 uv[4];
#pragma unroll
        for (int i = 0; i < 4; ++i)
            uv[i] = up[(size_t)(g * 4 + i) * 64];
#pragma unroll
        for (int i = 0; i < 4; ++i) {
            const int l = g * 4 + i;
#pragma unroll
            for (int dd = 0; dd < 4; ++dd) {
                const float dl = dls[w][dd][l];
                s[dd].x = fmaf(TEXP(c1[dd].x, c2[dd].x, c3[dd].x, dl), s[dd].x, dl * uv[i].x);
                s[dd].y = fmaf(TEXP(c1[dd].y, c2[dd].y, c3[dd].y, dl), s[dd].y, dl * uv[i].y);
                s[dd].z = fmaf(TEXP(c1[dd].z, c2[dd].z, c3[dd].z, dl), s[dd].z, dl * uv[i].z);
                s[dd].w = fmaf(TEXP(c1[dd].w, c2[dd].w, c3[dd].w, dl), s[dd].w, dl * uv[i].w);
            }
        }
    }

    const size_t rbb = ((size_t)(b * 256 + d0)) * NC + c;
#pragma unroll
    for (int dd = 0; dd < 4; ++dd) {
        *(float4*)(tc + (rbb + (size_t)dd * NC) * 256 + lane * 4) = s[dd];
        if (lane == 0) dsum[rbb + dd * NC] = dsv[dd];
    }
}

// ------------------- scan pass 2: combine chunk boundaries ------------------
// batch-load all 16 chunk records, combine in regs, store s_init in place.
__global__ __launch_bounds__(256) void k_scan2(
    const float* __restrict__ A, float* __restrict__ tc,
    const float* __restrict__ dsum)
{
    const int lane = threadIdx.x & 63;
    const int w    = threadIdx.x >> 6;
    const int blk  = blockIdx.x;
    const int b = blk & 3;
    const int d = (blk >> 2) * 4 + w;

    float4 a4 = *(const float4*)(A + (size_t)d * DS + lane * 4);
    a4.x *= LOG2E; a4.y *= LOG2E; a4.z *= LOG2E; a4.w *= LOG2E;

    const size_t rb = ((size_t)(b * 256 + d)) * NC;
    float4 T[NC];
    float  Dc[NC];
#pragma unroll
    for (int c = 0; c < NC; ++c) {
        T[c]  = *(const float4*)(tc + (rb + c) * 256 + lane * 4);
        Dc[c] = dsum[rb + c];
    }
    float4 s = make_float4(0.f, 0.f, 0.f, 0.f);
#pragma unroll
    for (int c = 0; c < NC; ++c) {
        float4 tmp = T[c];
        T[c] = s;                             // s_init[c]
        s.x = exp2f(a4.x * Dc[c]) * s.x + tmp.x;
        s.y = exp2f(a4.y * Dc[c]) * s.y + tmp.y;
        s.z = exp2f(a4.z * Dc[c]) * s.z + tmp.z;
        s.w = exp2f(a4.w * Dc[c]) * s.w + tmp.w;
    }
#pragma unroll
    for (int c = 0; c < NC; ++c)
        *(float4*)(tc + (rb + c) * 256 + lane * 4) = T[c];
}

// ------------------- scan pass 3: outputs from s_init -----------------------
// step partials written directly to wave-private T (stride 33: conflict-free);
// flush every 8 steps: 32-row column sums + 1 shfl.
__global__ __launch_bounds__(256, 4) void k_scan3(
    const float* __restrict__ dlt, const float* __restrict__ u,
    const float* __restrict__ cv, const float* __restrict__ A,
    const float* __restrict__ tc, float* __restrict__ y)
{
    const int lane = threadIdx.x & 63;
    const int w    = threadIdx.x >> 6;
    const int blk  = blockIdx.x;
    const int b  = blk & 3;
    const int c  = (blk >> 2) & 15;
    const int d0 = ((blk >> 6) * 4 + w) * 4;

    __shared__ float dls[4][4][LC];
    __shared__ float T[4][64][33];

    const size_t base = (size_t)b * LLEN * DI + (size_t)c * LC * DI;

    if (lane < LC) {
        float4 dv = *(const float4*)(dlt + base + (size_t)lane * DI + d0);
        dls[w][0][lane] = dv.x;
        dls[w][1][lane] = dv.y;
        dls[w][2][lane] = dv.z;
        dls[w][3][lane] = dv.w;
    }

    float4 c1[4], c2[4], c3[4];
#pragma unroll
    for (int dd = 0; dd < 4; ++dd) {
        float4 a = *(const float4*)(A + (size_t)(d0 + dd) * DS + lane * 4);
        c1[dd] = a;
        c2[dd] = make_float4(0.5f * a.x * a.x, 0.5f * a.y * a.y,
                             0.5f * a.z * a.z, 0.5f * a.w * a.w);
        c3[dd] = make_float4(c2[dd].x * a.x * (1.f / 3.f), c2[dd].y * a.y * (1.f / 3.f),
                             c2[dd].z * a.z * (1.f / 3.f), c2[dd].w * a.w * (1.f / 3.f));
    }

    const float4* up = (const float4*)(u + base) + lane;
    const float4* cp = (const float4*)(cv + base) + lane;
    float* yb = y + base;

    const size_t rbb = ((size_t)(b * 256 + d0)) * NC + c;
    float4 s[4];
#pragma unroll
    for (int dd = 0; dd < 4; ++dd)
        s[dd] = *(const float4*)(tc + (rbb + (size_t)dd * NC) * 256 + lane * 4);

    const int cc = lane & 31, seg = lane >> 5;

    for (int g = 0; g < LC / 4; ++g) {           // 8 groups of 4 steps
        float4 uv[4], cV[4];
#pragma unroll
        for (int i = 0; i < 4; ++i) {
            uv[i] = up[(size_t)(g * 4 + i) * 64];
            cV[i] = cp[(size_t)(g * 4 + i) * 64];
        }
#pragma unroll
        for (int i = 0; i < 4; ++i) {
            const int l = g * 4 + i;
            const int lc = l & 7;
#pragma unroll
            for (int dd = 0; dd < 4; ++dd) {
                const float dl = dls[w][dd][l];
                s[dd].x = fmaf(TEXP(c1[dd].x, c2[dd].x, c3[dd].x, dl), s[dd].x, dl * uv[i].x);
                s[dd].y = fmaf(TEXP(c1[dd].y, c2[dd].y, c3[dd].y, dl), s[dd].y, dl * uv[i].y);
                s[dd].z = fmaf(TEXP(c1[dd].z, c2[dd].z, c3[dd].z, dl), s[dd].z, dl * uv[i].z);
                s[dd].w = fmaf(TEXP(c1[dd].w, c2[dd].w, c3[dd].w, dl), s[dd].w, dl * uv[i].w);
                T[w][lane][dd * 8 + lc] =
                    fmaf(s[dd].w, cV[i].w, fmaf(s[dd].z, cV[i].z,
                         fmaf(s[dd].y, cV[i].y, s[dd].x * cV[i].x)));
            }
        }
        if (g & 1) {                             // flush 8 steps (cols full)
            float sm = 0.f;
#pragma unroll
            for (int r = 0; r < 32; ++r)
                sm += T[w][seg * 32 + r][cc];
            sm += __shfl_xor(sm, 32);
            if (lane < 32)
                yb[(size_t)((g >> 1) * 8 + (cc & 7)) * DI + d0 + (cc >> 3)] = sm;
        }
    }
}

// --------------------------- kernel 4: out GEMM (MFMA) ----------------------
__global__ __launch_bounds__(256) void k_out_mfma(
    const float* __restrict__ y, const float* __restrict__ szp,
    const short* __restrict__ W_outT, float* __restrict__ out)
{
    __shared__ short As[64][LP], Bs[64][LP];
    f32x4 acc[4] = {};
    const int tid  = threadIdx.x;
    const int w    = tid >> 6, lane = tid & 63;
    const int srow = tid >> 2, sseg = tid & 3;
    const int frow = lane & 15, fk = (lane >> 4) << 3;
    const int r0 = blockIdx.y * 64, n0 = blockIdx.x * 64;

    for (int k0 = 0; k0 < DI; k0 += BKK) {
        const size_t aoff = (size_t)(r0 + srow) * DI + k0 + sseg * 16;
        float4 y0 = *(const float4*)(y + aoff);
        float4 y1 = *(const float4*)(y + aoff + 4);
        float4 y2 = *(const float4*)(y + aoff + 8);
        float4 y3 = *(const float4*)(y + aoff + 12);
        float4 s0 = *(const float4*)(szp + aoff);
        float4 s1 = *(const float4*)(szp + aoff + 4);
        float4 s2 = *(const float4*)(szp + aoff + 8);
        float4 s3 = *(const float4*)(szp + aoff + 12);
        const short* bg = W_outT + (size_t)(n0 + srow) * DI + k0 + sseg * 16;
        bf16x8 b0 = *(const bf16x8*)bg;
        bf16x8 b1 = *(const bf16x8*)(bg + 8);
        bf16x8 a0, a1;
        a0[0] = f2bf(y0.x * s0.x); a0[1] = f2bf(y0.y * s0.y);
        a0[2] = f2bf(y0.z * s0.z); a0[3] = f2bf(y0.w * s0.w);
        a0[4] = f2bf(y1.x * s1.x); a0[5] = f2bf(y1.y * s1.y);
        a0[6] = f2bf(y1.z * s1.z); a0[7] = f2bf(y1.w * s1.w);
        a1[0] = f2bf(y2.x * s2.x); a1[1] = f2bf(y2.y * s2.y);
        a1[2] = f2bf(y2.z * s2.z); a1[3] = f2bf(y2.w * s2.w);
        a1[4] = f2bf(y3.x * s3.x); a1[5] = f2bf(y3.y * s3.y);
        a1[6] = f2bf(y3.z * s3.z); a1[7] = f2bf(y3.w * s3.w);
        __syncthreads();
        *(bf16x8*)&As[srow][sseg * 16]     = a0;
        *(bf16x8*)&As[srow][sseg * 16 + 8] = a1;
        *(bf16x8*)&Bs[srow][sseg * 16]     = b0;
        *(bf16x8*)&Bs[srow][sseg * 16 + 8] = b1;
        __syncthreads();
#pragma unroll
        for (int kk = 0; kk < BKK; kk += 32) {
            bf16x8 af = *(const bf16x8*)&As[w * 16 + frow][kk + fk];
#pragma unroll
            for (int ct = 0; ct < 4; ++ct) {
                bf16x8 bfr = *(const bf16x8*)&Bs[ct * 16 + frow][kk + fk];
                acc[ct] = __builtin_amdgcn_mfma_f32_16x16x32_bf16(af, bfr, acc[ct], 0, 0, 0);
            }
        }
    }

    const int rr = r0 + w * 16 + (lane >> 4) * 4;
    const int c0 = n0 + (lane & 15);
#pragma unroll
    for (int ct = 0; ct < 4; ++ct) {
        const int c = c0 + ct * 16;
#pragma unroll
        for (int rg = 0; rg < 4; ++rg)
            out[(size_t)(rr + rg) * DM + c] = acc[ct][rg];
    }
}

// ---------------------------------------------------------------------------
extern "C" void kernel_launch(void* const* d_in, const int* in_sizes, int n_in,
                              void* d_out, int out_size, void* d_ws, size_t ws_size,
                              hipStream_t stream)
{
    const float* x       = (const float*)d_in[0];
    const float* W_in    = (const float*)d_in[1];
    const float* W_delta = (const float*)d_in[2];
    const float* W_B     = (const float*)d_in[3];
    const float* W_C     = (const float*)d_in[4];
    const float* W_out   = (const float*)d_in[5];
    const float* A       = (const float*)d_in[6];
    // d_in[7] = D, unused by the reference scan

    float* out = (float*)d_out;
    float* ws  = (float*)d_ws;

    const size_t S = (size_t)MROWS * DI;   // 524288 floats per plane (2 MB)
    float* xs  = ws;
    float* sz  = ws + S;
    float* dlt = ws + 2 * S;
    float* u   = ws + 3 * S;
    float* cv  = ws + 4 * S;
    float* yv  = ws + 5 * S;
    float* tc  = ws + 6 * S;                              // 1024*16*256 = 16 MB
    float* dsm = tc + (size_t)1024 * NC * 256;            // 16384 floats

    short* xs_bf  = (short*)(dsm + (size_t)1024 * NC);    // 2048*256
    short* WdbcT  = xs_bf + (size_t)MROWS * DI;           // 768*256
    short* W_outT = WdbcT + (size_t)768 * DI;             // 128*256

    k_proj_mfma<<<dim3(15, 32), 256, 0, stream>>>(x, W_in, W_delta, W_B, W_C, W_out,
                                                  xs, xs_bf, sz, WdbcT, W_outT);
    k_dbc_mfma <<<dim3(12, 32), 256, 0, stream>>>(xs_bf, WdbcT, xs, dlt, u, cv);
    k_scan1    <<<dim3(1024), 256, 0, stream>>>(dlt, u, A, tc, dsm);
    k_scan2    <<<dim3(256), 256, 0, stream>>>(A, tc, dsm);
    k_scan3    <<<dim3(1024), 256, 0, stream>>>(dlt, u, cv, A, tc, yv);
    k_out_mfma <<<dim3(2, 32), 256, 0, stream>>>(yv, sz, W_outT, out);
}